// Round 8
// baseline (1460.780 us; speedup 1.0000x reference)
//
#include <hip/hip_runtime.h>
#include <cstdint>
#include <cstddef>

// DGCNN forward. R8: conv de-duplicated — edge conv = dense per-point GEMM
// (Y = X·W1^T, T = X·(W2-W1)^T + b, split-bf16 MFMA) + streaming edge_reduce
// (max/sum/sumsq over gathered Y rows; max_k(Y_j+T_n) = T_n + max_k Y_j).
// 20x less GEMM work than R7's gathered conv. dist/select/final unchanged.

constexpr int NB = 8;
constexpr int NP = 2048;
constexpr int KK = 20;

typedef short bf16x8 __attribute__((ext_vector_type(8)));
typedef float f32x16 __attribute__((ext_vector_type(16)));

__device__ __forceinline__ f32x16 MF(bf16x8 a, bf16x8 b, f32x16 c) {
  return __builtin_amdgcn_mfma_f32_32x32x16_bf16(a, b, c, 0, 0, 0);
}
__device__ __forceinline__ unsigned short bfh(float f) {
  return (unsigned short)(__float_as_uint(f) >> 16);  // truncating bf16
}
__device__ __forceinline__ float bff(unsigned short u) {
  return __uint_as_float(((unsigned)u) << 16);
}
__device__ __forceinline__ void split2(float v, unsigned short& h, unsigned short& l) {
  h = bfh(v); l = bfh(v - bff(h));
}
__device__ __forceinline__ void stage16(unsigned short* dst, const unsigned short* src) {
  *reinterpret_cast<uint4*>(dst) = *reinterpret_cast<const uint4*>(src);
}

#define FMA16(AV, BV, ACC)                                          \
  {                                                                 \
    const float _a[4] = {AV.x, AV.y, AV.z, AV.w};                   \
    const float _b[4] = {BV.x, BV.y, BV.z, BV.w};                   \
    _Pragma("unroll")                                               \
    for (int _e = 0; _e < 4; ++_e) {                                \
      _Pragma("unroll")                                             \
      for (int _f = 0; _f < 4; ++_f)                                \
        ACC[_e][_f] = fmaf(_a[_e], _b[_f], ACC[_e][_f]);            \
    }                                                               \
  }

// ---------------- pad x -> x4 ----------------
__global__ __launch_bounds__(256) void pad_kernel(const float* __restrict__ x,
                                                  float* __restrict__ x4) {
  const int p = blockIdx.x * 256 + threadIdx.x;
  float4 v;
  v.x = x[p * 3 + 0]; v.y = x[p * 3 + 1]; v.z = x[p * 3 + 2]; v.w = 0.f;
  *reinterpret_cast<float4*>(x4 + (size_t)p * 4) = v;
}

// ---------------- weight splits ----------------
template<int O, int C>
__global__ __launch_bounds__(256) void wsplit_conv(const float* __restrict__ W,
    unsigned short* __restrict__ w1h, unsigned short* __restrict__ w1l,
    unsigned short* __restrict__ wdh, unsigned short* __restrict__ wdl) {
  const int id = blockIdx.x * 256 + threadIdx.x;  // O*C
  const int o = id / C, c = id % C;
  const float w1 = W[o * 2 * C + c];
  const float w2 = W[o * 2 * C + C + c];
  unsigned short h, l;
  split2(w1, h, l); w1h[id] = h; w1l[id] = l;
  split2(w2 - w1, h, l); wdh[id] = h; wdl[id] = l;
}

__global__ __launch_bounds__(256) void wsplit_final(const float* __restrict__ Wf,
    unsigned short* __restrict__ wfh, unsigned short* __restrict__ wfl) {
  const int id = blockIdx.x * 256 + threadIdx.x;  // 1024*512
  unsigned short h, l;
  split2(Wf[id], h, l); wfh[id] = h; wfl[id] = l;
}

// ---------------- norms ----------------
__global__ __launch_bounds__(256) void norms4_kernel(const float* __restrict__ X,
                                                     float* __restrict__ out) {
  const int g = blockIdx.x * 256 + threadIdx.x;
  const float4 v = *reinterpret_cast<const float4*>(X + (size_t)g * 4);
  out[g] = v.x * v.x + v.y * v.y + v.z * v.z;
}

template<int C>
__global__ __launch_bounds__(256) void norms_planes(const unsigned short* __restrict__ xh,
    const unsigned short* __restrict__ xl, int colbase, float* __restrict__ out) {
  const int g = blockIdx.x * 256 + threadIdx.x;
  const size_t base = (size_t)g * 512 + colbase;
  float s = 0.f;
#pragma unroll
  for (int k8 = 0; k8 < C / 8; ++k8) {
    const uint4 uh = *reinterpret_cast<const uint4*>(xh + base + k8 * 8);
    const uint4 ul = *reinterpret_cast<const uint4*>(xl + base + k8 * 8);
    const unsigned hs[4] = {uh.x, uh.y, uh.z, uh.w};
    const unsigned ls[4] = {ul.x, ul.y, ul.z, ul.w};
#pragma unroll
    for (int q = 0; q < 4; ++q) {
      const float v0 = __uint_as_float(hs[q] << 16) + __uint_as_float(ls[q] << 16);
      const float v1 = __uint_as_float(hs[q] & 0xffff0000u) + __uint_as_float(ls[q] & 0xffff0000u);
      s = fmaf(v0, v0, s);
      s = fmaf(v1, v1, s);
    }
  }
  out[g] = s;
}

// ---------------- dist L0 (C=3, fp32 vector) ----------------
__global__ __launch_bounds__(256) void dist0_kernel(const float* __restrict__ X4,
    const float* __restrict__ norms, float* __restrict__ negd, int bbase) {
  __shared__ float sb[640];
  const int t = threadIdx.x, tr = t & 15, tcq = t >> 4;
  const int z = blockIdx.z, b = bbase + z;
  const int i0 = blockIdx.x * 64, j0 = blockIdx.y * 64;
  const int c4 = t >> 6, row = t & 63;
  if (t < 64) sb[512 + t] = norms[b * NP + i0 + t];
  else if (t < 128) sb[512 + t] = norms[b * NP + j0 + (t - 64)];
  sb[c4 * 64 + row] = X4[(size_t)(b * NP + i0 + row) * 4 + c4];
  sb[256 + c4 * 64 + row] = X4[(size_t)(b * NP + j0 + row) * 4 + c4];
  __syncthreads();
  float acc[4][4] = {};
#pragma unroll
  for (int c = 0; c < 4; ++c) {
    const float4 a = *reinterpret_cast<const float4*>(sb + c * 64 + tr * 4);
    const float4 bb = *reinterpret_cast<const float4*>(sb + 256 + c * 64 + tcq * 4);
    FMA16(a, bb, acc);
  }
#pragma unroll
  for (int e = 0; e < 4; ++e) {
    const int rowi = tr * 4 + e;
    const float ni = sb[512 + rowi];
    float4 nd;
    nd.x = 2.f * acc[e][0] - ni - sb[576 + tcq * 4 + 0];
    nd.y = 2.f * acc[e][1] - ni - sb[576 + tcq * 4 + 1];
    nd.z = 2.f * acc[e][2] - ni - sb[576 + tcq * 4 + 2];
    nd.w = 2.f * acc[e][3] - ni - sb[576 + tcq * 4 + 3];
    *reinterpret_cast<float4*>(negd + ((size_t)z * NP + i0 + rowi) * NP + j0 + tcq * 4) = nd;
  }
}

// ---------------- dist MFMA (l>=1) ----------------
template<int C>
__global__ __launch_bounds__(256) void dist_mfma(const unsigned short* __restrict__ xh,
    const unsigned short* __restrict__ xl, int colbase,
    const float* __restrict__ norms, float* __restrict__ negd, int bbase) {
  constexpr int K8 = C / 8;
  __shared__ __align__(16) unsigned short sb[4 * K8 * 512];
  __shared__ float fn[128];
  unsigned short* sAh = sb;
  unsigned short* sAl = sb + K8 * 512;
  unsigned short* sBh = sb + 2 * K8 * 512;
  unsigned short* sBl = sb + 3 * K8 * 512;

  const int t = threadIdx.x, lane = t & 63, w = t >> 6;
  const int half = lane >> 5, l31 = lane & 31;
  const int rt = (w >> 1) * 32, tc = (w & 1) * 32;
  const int z = blockIdx.z, b = bbase + z;
  const int i0 = blockIdx.x * 64, j0 = blockIdx.y * 64;

  if (t < 64) fn[t] = norms[b * NP + i0 + t];
  else if (t < 128) fn[t] = norms[b * NP + j0 + (t - 64)];

  {
    const int r = t & 63;
    const size_t gi = ((size_t)(b * NP + i0 + r)) * 512 + colbase;
    const size_t gj = ((size_t)(b * NP + j0 + r)) * 512 + colbase;
#pragma unroll
    for (int i = 0; i < K8 / 4; ++i) {
      const int k8 = (t >> 6) + 4 * i;
      stage16(sAh + (k8 * 64 + r) * 8, xh + gi + k8 * 8);
      stage16(sAl + (k8 * 64 + r) * 8, xl + gi + k8 * 8);
      stage16(sBh + (k8 * 64 + r) * 8, xh + gj + k8 * 8);
      stage16(sBl + (k8 * 64 + r) * 8, xl + gj + k8 * 8);
    }
  }
  __syncthreads();

  f32x16 acc;
#pragma unroll
  for (int i = 0; i < 16; ++i) acc[i] = 0.f;
#pragma unroll
  for (int cc = 0; cc < K8 / 2; ++cc) {
    const int k8 = cc * 2 + half;
    const bf16x8 ah = *reinterpret_cast<const bf16x8*>(sAh + (k8 * 64 + rt + l31) * 8);
    const bf16x8 al = *reinterpret_cast<const bf16x8*>(sAl + (k8 * 64 + rt + l31) * 8);
    const bf16x8 bh = *reinterpret_cast<const bf16x8*>(sBh + (k8 * 64 + tc + l31) * 8);
    const bf16x8 bl = *reinterpret_cast<const bf16x8*>(sBl + (k8 * 64 + tc + l31) * 8);
    acc = MF(ah, bh, acc);
    acc = MF(ah, bl, acc);
    acc = MF(al, bh, acc);
  }

  const int col = tc + l31;
  const float nj = fn[64 + col];
#pragma unroll
  for (int i = 0; i < 16; ++i) {
    const int row = rt + (i & 3) + 8 * (i >> 2) + 4 * half;
    negd[((size_t)z * NP + i0 + row) * NP + j0 + col] = 2.f * acc[i] - fn[row] - nj;
  }
}

// ---------------- knn select (R6, unchanged) ----------------
__global__ __launch_bounds__(256) void knn_select_kernel(const float* __restrict__ negd,
    int* __restrict__ idxout, int bbase) {
  const int t = threadIdx.x, lane = t & 63, w = t >> 6;
  const int rloc = blockIdx.x * 4 + w;
  const float* rowp = negd + (size_t)rloc * NP + lane * 32;

  float v[32];
#pragma unroll
  for (int m = 0; m < 8; ++m) {
    const float4 d = *reinterpret_cast<const float4*>(rowp + m * 4);
    v[m * 4 + 0] = d.x; v[m * 4 + 1] = d.y; v[m * 4 + 2] = d.z; v[m * 4 + 3] = d.w;
  }
  float lm = v[0]; int lp = 0;
#pragma unroll
  for (int e = 1; e < 32; ++e)
    if (v[e] > lm) { lm = v[e]; lp = e; }

  int* op = idxout + (size_t)(bbase * NP + rloc) * KK;
  for (int r = 0; r < KK; ++r) {
    float wm = lm;
#pragma unroll
    for (int o = 1; o < 64; o <<= 1) wm = fmaxf(wm, __shfl_xor(wm, o));
    const unsigned long long bal = __ballot(lm == wm);
    const int wl = __ffsll(bal) - 1;
    if (lane == wl) {
      op[r] = lane * 32 + lp;
#pragma unroll
      for (int e = 0; e < 32; ++e)
        if (e == lp) v[e] = -__builtin_inff();
      lm = v[0]; lp = 0;
#pragma unroll
      for (int e = 1; e < 32; ++e)
        if (v[e] > lm) { lm = v[e]; lp = e; }
    }
  }
}

// ---------------- per-point GEMM, L0 (C=3, fp32 vector) ----------------
__global__ __launch_bounds__(256) void pt_gemm0(const float* __restrict__ x,
    const float* __restrict__ W, const float* __restrict__ bias,
    float* __restrict__ Y, float* __restrict__ T) {
  const int t = threadIdx.x;
  const int o = t & 63;
  const int g = blockIdx.x * 4 + (t >> 6);  // 0..16383
  const float x0 = x[(size_t)g * 3 + 0], x1 = x[(size_t)g * 3 + 1], x2 = x[(size_t)g * 3 + 2];
  const float w10 = W[o * 6 + 0], w11 = W[o * 6 + 1], w12 = W[o * 6 + 2];
  const float w20 = W[o * 6 + 3], w21 = W[o * 6 + 4], w22 = W[o * 6 + 5];
  Y[(size_t)g * 64 + o] = w10 * x0 + w11 * x1 + w12 * x2;
  T[(size_t)g * 64 + o] = (w20 - w10) * x0 + (w21 - w11) * x1 + (w22 - w12) * x2 + bias[o];
}

// ---------------- per-point GEMM (l>=1, MFMA): Y = X W1^T, T = X Wd^T + b ----
template<int C, int O>
__global__ __launch_bounds__(256) void pt_gemm(const unsigned short* __restrict__ xh,
    const unsigned short* __restrict__ xl, int colbase,
    const unsigned short* __restrict__ w1h, const unsigned short* __restrict__ w1l,
    const unsigned short* __restrict__ wdh, const unsigned short* __restrict__ wdl,
    const float* __restrict__ bias, float* __restrict__ Y, float* __restrict__ T) {
  constexpr int K8 = C / 8;
  __shared__ __align__(16) unsigned short sb[4 * K8 * 512];
  unsigned short* sXh = sb;
  unsigned short* sXl = sb + K8 * 512;
  unsigned short* sWh = sb + 2 * K8 * 512;
  unsigned short* sWl = sb + 3 * K8 * 512;

  const int t = threadIdx.x, lane = t & 63, w = t >> 6;
  const int half = lane >> 5, l31 = lane & 31;
  const int rt = (w >> 1) * 32, tc = (w & 1) * 32;
  const int n0 = blockIdx.x * 64, o0 = blockIdx.y * 64;
  const int r = t & 63, k80 = t >> 6;
  const int col = o0 + tc + l31;

  {
    const size_t gx = ((size_t)(n0 + r)) * 512 + colbase;
    const size_t gw = (size_t)(o0 + r) * C;
#pragma unroll
    for (int i = 0; i < K8 / 4; ++i) {
      const int k8 = k80 + 4 * i;
      stage16(sXh + (k8 * 64 + r) * 8, xh + gx + k8 * 8);
      stage16(sXl + (k8 * 64 + r) * 8, xl + gx + k8 * 8);
      stage16(sWh + (k8 * 64 + r) * 8, w1h + gw + k8 * 8);
      stage16(sWl + (k8 * 64 + r) * 8, w1l + gw + k8 * 8);
    }
  }
  __syncthreads();
  f32x16 acc;
#pragma unroll
  for (int i = 0; i < 16; ++i) acc[i] = 0.f;
#pragma unroll
  for (int cc = 0; cc < K8 / 2; ++cc) {
    const int k8 = cc * 2 + half;
    const bf16x8 ah = *reinterpret_cast<const bf16x8*>(sXh + (k8 * 64 + rt + l31) * 8);
    const bf16x8 al = *reinterpret_cast<const bf16x8*>(sXl + (k8 * 64 + rt + l31) * 8);
    const bf16x8 bh = *reinterpret_cast<const bf16x8*>(sWh + (k8 * 64 + tc + l31) * 8);
    const bf16x8 bl = *reinterpret_cast<const bf16x8*>(sWl + (k8 * 64 + tc + l31) * 8);
    acc = MF(ah, bh, acc); acc = MF(ah, bl, acc); acc = MF(al, bh, acc);
  }
#pragma unroll
  for (int i = 0; i < 16; ++i) {
    const int row = n0 + rt + (i & 3) + 8 * (i >> 2) + 4 * half;
    Y[(size_t)row * O + col] = acc[i];
  }

  __syncthreads();
  {
    const size_t gw = (size_t)(o0 + r) * C;
#pragma unroll
    for (int i = 0; i < K8 / 4; ++i) {
      const int k8 = k80 + 4 * i;
      stage16(sWh + (k8 * 64 + r) * 8, wdh + gw + k8 * 8);
      stage16(sWl + (k8 * 64 + r) * 8, wdl + gw + k8 * 8);
    }
  }
  __syncthreads();
#pragma unroll
  for (int i = 0; i < 16; ++i) acc[i] = 0.f;
#pragma unroll
  for (int cc = 0; cc < K8 / 2; ++cc) {
    const int k8 = cc * 2 + half;
    const bf16x8 ah = *reinterpret_cast<const bf16x8*>(sXh + (k8 * 64 + rt + l31) * 8);
    const bf16x8 al = *reinterpret_cast<const bf16x8*>(sXl + (k8 * 64 + rt + l31) * 8);
    const bf16x8 bh = *reinterpret_cast<const bf16x8*>(sWh + (k8 * 64 + tc + l31) * 8);
    const bf16x8 bl = *reinterpret_cast<const bf16x8*>(sWl + (k8 * 64 + tc + l31) * 8);
    acc = MF(ah, bh, acc); acc = MF(ah, bl, acc); acc = MF(al, bh, acc);
  }
  const float bv = bias[col];
#pragma unroll
  for (int i = 0; i < 16; ++i) {
    const int row = n0 + rt + (i & 3) + 8 * (i >> 2) + 4 * half;
    T[(size_t)row * O + col] = acc[i] + bv;
  }
}

// ---------------- edge reduce: max/sum/sumsq over gathered Y rows ----------------
// out[n,o] = T[n,o] + ... max over k of (Y[idx[n,k],o] + T[n,o]); stats over all (n,k).
template<int O>
__global__ __launch_bounds__(256) void edge_reduce(const float* __restrict__ Y,
    const float* __restrict__ T, const int* __restrict__ idx,
    float* __restrict__ outmax, float* __restrict__ ssum, float* __restrict__ ssq) {
  constexpr int PTS = 32;
  constexpr int NG = 256 / O;
  const int t = threadIdx.x;
  const int o = t % O, ng = t / O;
  const int g0 = blockIdx.x * PTS;
  float sacc = 0.f, qacc = 0.f;
  for (int p = ng; p < PTS; p += NG) {
    const int g = g0 + p;
    const int b = g >> 11;
    const float tv = T[(size_t)g * O + o];
    const int* ip = idx + (size_t)g * KK;
    float mx = -__builtin_inff();
#pragma unroll 5
    for (int k = 0; k < KK; ++k) {
      const int j = b * NP + ip[k];
      const float h = Y[(size_t)j * O + o] + tv;
      mx = fmaxf(mx, h);
      sacc += h;
      qacc = fmaf(h, h, qacc);
    }
    outmax[(size_t)g * O + o] = mx;
  }
  atomicAdd(ssum + o, sacc);
  atomicAdd(ssq + o, qacc);
}

// ---------------- bn + leaky relu -> bf16 planes ----------------
template<int O>
__global__ __launch_bounds__(256) void bnrelu_kernel(const float* __restrict__ fA,
    const float* __restrict__ ssum, const float* __restrict__ ssq,
    const float* __restrict__ g, const float* __restrict__ be,
    unsigned short* __restrict__ xh, unsigned short* __restrict__ xl, int colbase) {
  constexpr float INV = 1.0f / 327680.0f;  // B*N*K
  const int t4 = blockIdx.x * 256 + threadIdx.x;
  const int e0 = t4 * 4;
  const int r = e0 / O, c = e0 % O;
  const float4 h1 = *reinterpret_cast<const float4*>(fA + (size_t)r * O + c);
  float hv[4] = {h1.x, h1.y, h1.z, h1.w};
  unsigned short hh[4], ll[4];
#pragma unroll
  for (int j = 0; j < 4; ++j) {
    const int col = c + j;
    const float m = ssum[col] * INV;
    const float v = ssq[col] * INV - m * m;
    const float sc = g[col] / sqrtf(v + 1e-5f);
    float val = (hv[j] - m) * sc + be[col];
    val = (val >= 0.f) ? val : 0.2f * val;
    split2(val, hh[j], ll[j]);
  }
  const size_t ob = (size_t)r * 512 + colbase + c;
  uint2 ph, pl;
  ph.x = (unsigned)hh[0] | ((unsigned)hh[1] << 16);
  ph.y = (unsigned)hh[2] | ((unsigned)hh[3] << 16);
  pl.x = (unsigned)ll[0] | ((unsigned)ll[1] << 16);
  pl.y = (unsigned)ll[2] | ((unsigned)ll[3] << 16);
  *reinterpret_cast<uint2*>(xh + ob) = ph;
  *reinterpret_cast<uint2*>(xl + ob) = pl;
}

// ---------------- final conv + global max pool (MFMA) ----------------
__global__ __launch_bounds__(256) void final_mfma(const unsigned short* __restrict__ xh,
    const unsigned short* __restrict__ xl, const unsigned short* __restrict__ wfh,
    const unsigned short* __restrict__ wfl, unsigned* __restrict__ outenc) {
  __shared__ __align__(16) unsigned short sb[4 * 4096];
  __shared__ float fr[128];
  unsigned short* sAh = sb;
  unsigned short* sAl = sb + 4096;
  unsigned short* sBh = sb + 8192;
  unsigned short* sBl = sb + 12288;
  const int t = threadIdx.x, lane = t & 63, w = t >> 6;
  const int half = lane >> 5, l31 = lane & 31;
  const int rt = (w >> 1) * 32, tc = (w & 1) * 32;
  const int b = blockIdx.z, n0 = blockIdx.x * 64, o0 = blockIdx.y * 64;
  const int r = t & 63, k80 = t >> 6;

  f32x16 acc;
#pragma unroll
  for (int i = 0; i < 16; ++i) acc[i] = 0.f;

  for (int cc = 0; cc < 8; ++cc) {
    __syncthreads();
    const size_t ga = ((size_t)(b * NP + n0 + r)) * 512 + cc * 64;
    const size_t gb = ((size_t)(o0 + r)) * 512 + cc * 64;
#pragma unroll
    for (int i = 0; i < 2; ++i) {
      const int k8 = k80 + 4 * i;
      stage16(sAh + (k8 * 64 + r) * 8, xh + ga + k8 * 8);
      stage16(sAl + (k8 * 64 + r) * 8, xl + ga + k8 * 8);
      stage16(sBh + (k8 * 64 + r) * 8, wfh + gb + k8 * 8);
      stage16(sBl + (k8 * 64 + r) * 8, wfl + gb + k8 * 8);
    }
    __syncthreads();
#pragma unroll
    for (int ch = 0; ch < 4; ++ch) {
      const int k8 = ch * 2 + half;
      const bf16x8 ah = *reinterpret_cast<const bf16x8*>(sAh + (k8 * 64 + rt + l31) * 8);
      const bf16x8 al = *reinterpret_cast<const bf16x8*>(sAl + (k8 * 64 + rt + l31) * 8);
      const bf16x8 bh = *reinterpret_cast<const bf16x8*>(sBh + (k8 * 64 + tc + l31) * 8);
      const bf16x8 bl = *reinterpret_cast<const bf16x8*>(sBl + (k8 * 64 + tc + l31) * 8);
      acc = MF(ah, bh, acc); acc = MF(ah, bl, acc); acc = MF(al, bh, acc);
    }
  }
  float M = acc[0];
#pragma unroll
  for (int i = 1; i < 16; ++i) M = fmaxf(M, acc[i]);
  M = fmaxf(M, __shfl_xor(M, 32));
  fr[w * 32 + l31] = M;
  __syncthreads();
  if (t < 64) {
    const float Mc = fmaxf(fr[t], fr[64 + t]);
    const unsigned ub = __float_as_uint(Mc);
    const unsigned key = (ub & 0x80000000u) ? ~ub : (ub | 0x80000000u);
    atomicMax(outenc + b * 1024 + o0 + t, key);
  }
}

__global__ __launch_bounds__(256) void decode_kernel(const unsigned int* __restrict__ enc,
    const float* __restrict__ bf, float* __restrict__ out) {
  const int gid = blockIdx.x * 256 + threadIdx.x;  // 8192
  const unsigned key = enc[gid];
  const unsigned ubits = (key & 0x80000000u) ? (key & 0x7fffffffu) : ~key;
  out[gid] = __uint_as_float(ubits) + bf[gid & 1023];
}

// ---------------- launch ----------------
extern "C" void kernel_launch(void* const* d_in, const int* in_sizes, int n_in,
                              void* d_out, int out_size, void* d_ws, size_t ws_size,
                              hipStream_t stream) {
  (void)in_sizes; (void)n_in; (void)out_size; (void)ws_size;
  const float* x   = (const float*)d_in[0];
  const float* W0  = (const float*)d_in[1];
  const float* b0  = (const float*)d_in[2];
  const float* g0  = (const float*)d_in[3];
  const float* be0 = (const float*)d_in[4];
  const float* W1  = (const float*)d_in[5];
  const float* b1  = (const float*)d_in[6];
  const float* g1  = (const float*)d_in[7];
  const float* be1 = (const float*)d_in[8];
  const float* W2  = (const float*)d_in[9];
  const float* b2  = (const float*)d_in[10];
  const float* g2  = (const float*)d_in[11];
  const float* be2 = (const float*)d_in[12];
  const float* W3  = (const float*)d_in[13];
  const float* b3  = (const float*)d_in[14];
  const float* g3  = (const float*)d_in[15];
  const float* be3 = (const float*)d_in[16];
  const float* Wf  = (const float*)d_in[17];
  const float* bf  = (const float*)d_in[18];

  float* wsf = (float*)d_ws;
  int* idxb = (int*)d_ws;                               // 327,680 ints
  float* norms = wsf + 327680;                          // 16384
  float* stats = norms + 16384;                         // 2048
  unsigned* outenc = (unsigned*)(stats + 2048);         // 8192
  float* x4 = (float*)(outenc + 8192);                  // 65536
  float* featA = x4 + 65536;                            // 16384*256 (16.8 MB)
  float* negd = featA + (size_t)4194304;                // 2*2048*2048 (33.5 MB)
  float* Yb = negd;                                     // alias: Y [16384][O<=256]
  float* Tb = negd + 4194304;                           // alias: T
  unsigned short* xh = (unsigned short*)(negd + 8388608);  // [16384][512]
  unsigned short* xl = xh + 8388608;
  unsigned short* wb1 = xl + 8388608;                   // L1: 4 * 64*64
  unsigned short* wb2 = wb1 + 16384;                    // L2: 4 * 128*64
  unsigned short* wb3 = wb2 + 32768;                    // L3: 4 * 256*128
  unsigned short* wfh = wb3 + 131072;                   // 1024*512
  unsigned short* wfl = wfh + 524288;

  hipMemsetAsync(stats, 0, 2048 * sizeof(float), stream);
  hipMemsetAsync(outenc, 0, 8192 * sizeof(unsigned), stream);

  const dim3 blk(256, 1, 1);
  const dim3 ggrid(32, 32, 2);
  const dim3 sgrid(1024, 1, 1);
  const dim3 ergrid(512, 1, 1);

  pad_kernel<<<dim3(64), blk, 0, stream>>>(x, x4);
  wsplit_conv<64, 64><<<dim3(16), blk, 0, stream>>>(W1, wb1, wb1 + 4096, wb1 + 8192, wb1 + 12288);
  wsplit_conv<128, 64><<<dim3(32), blk, 0, stream>>>(W2, wb2, wb2 + 8192, wb2 + 16384, wb2 + 24576);
  wsplit_conv<256, 128><<<dim3(128), blk, 0, stream>>>(W3, wb3, wb3 + 32768, wb3 + 65536, wb3 + 98304);
  wsplit_final<<<dim3(2048), blk, 0, stream>>>(Wf, wfh, wfl);

  // Layer 0 (C=3 -> 64, out cols [0,64))
  norms4_kernel<<<dim3(64), blk, 0, stream>>>(x4, norms);
  for (int cb = 0; cb < 4; ++cb) {
    dist0_kernel<<<ggrid, blk, 0, stream>>>(x4, norms, negd, 2 * cb);
    knn_select_kernel<<<sgrid, blk, 0, stream>>>(negd, idxb, 2 * cb);
  }
  pt_gemm0<<<dim3(4096), blk, 0, stream>>>(x, W0, b0, Yb, Tb);
  edge_reduce<64><<<ergrid, blk, 0, stream>>>(Yb, Tb, idxb, featA, stats, stats + 256);
  bnrelu_kernel<64><<<dim3(1024), blk, 0, stream>>>(featA, stats, stats + 256, g0, be0, xh, xl, 0);

  // Layer 1 (64 -> 64, in cols [0,64), out [64,128))
  norms_planes<64><<<dim3(64), blk, 0, stream>>>(xh, xl, 0, norms);
  for (int cb = 0; cb < 4; ++cb) {
    dist_mfma<64><<<ggrid, blk, 0, stream>>>(xh, xl, 0, norms, negd, 2 * cb);
    knn_select_kernel<<<sgrid, blk, 0, stream>>>(negd, idxb, 2 * cb);
  }
  pt_gemm<64, 64><<<dim3(256, 1), blk, 0, stream>>>(xh, xl, 0,
      wb1, wb1 + 4096, wb1 + 8192, wb1 + 12288, b1, Yb, Tb);
  edge_reduce<64><<<ergrid, blk, 0, stream>>>(Yb, Tb, idxb, featA, stats + 512, stats + 768);
  bnrelu_kernel<64><<<dim3(1024), blk, 0, stream>>>(featA, stats + 512, stats + 768, g1, be1,
                                                    xh, xl, 64);

  // Layer 2 (64 -> 128, in cols [64,128), out [128,256))
  norms_planes<64><<<dim3(64), blk, 0, stream>>>(xh, xl, 64, norms);
  for (int cb = 0; cb < 4; ++cb) {
    dist_mfma<64><<<ggrid, blk, 0, stream>>>(xh, xl, 64, norms, negd, 2 * cb);
    knn_select_kernel<<<sgrid, blk, 0, stream>>>(negd, idxb, 2 * cb);
  }
  pt_gemm<64, 128><<<dim3(256, 2), blk, 0, stream>>>(xh, xl, 64,
      wb2, wb2 + 8192, wb2 + 16384, wb2 + 24576, b2, Yb, Tb);
  edge_reduce<128><<<ergrid, blk, 0, stream>>>(Yb, Tb, idxb, featA, stats + 1024, stats + 1280);
  bnrelu_kernel<128><<<dim3(2048), blk, 0, stream>>>(featA, stats + 1024, stats + 1280, g2, be2,
                                                     xh, xl, 128);

  // Layer 3 (128 -> 256, in cols [128,256), out [256,512))
  norms_planes<128><<<dim3(64), blk, 0, stream>>>(xh, xl, 128, norms);
  for (int cb = 0; cb < 4; ++cb) {
    dist_mfma<128><<<ggrid, blk, 0, stream>>>(xh, xl, 128, norms, negd, 2 * cb);
    knn_select_kernel<<<sgrid, blk, 0, stream>>>(negd, idxb, 2 * cb);
  }
  pt_gemm<128, 256><<<dim3(256, 4), blk, 0, stream>>>(xh, xl, 128,
      wb3, wb3 + 32768, wb3 + 65536, wb3 + 98304, b3, Yb, Tb);
  edge_reduce<256><<<ergrid, blk, 0, stream>>>(Yb, Tb, idxb, featA, stats + 1536, stats + 1792);
  bnrelu_kernel<256><<<dim3(4096), blk, 0, stream>>>(featA, stats + 1536, stats + 1792, g3, be3,
                                                     xh, xl, 256);

  // Final 1x1 conv + global max pool
  final_mfma<<<dim3(32, 16, 8), blk, 0, stream>>>(xh, xl, wfh, wfl, outenc);
  decode_kernel<<<dim3(32), blk, 0, stream>>>(outenc, bf, (float*)d_out);
}

// Round 10
// 1327.958 us; speedup vs baseline: 1.1000x; 1.1000x over previous
//
#include <hip/hip_runtime.h>
#include <cstdint>
#include <cstddef>

// DGCNN forward. R10 = R9 structure + norm-consistency fix:
// bnrelu's fused next-layer norm now accumulates the RECONSTRUCTED value
// (bf16 hi + bf16 lo), matching what dist_mfma's Gram consumes. R9 used the
// fp32 pre-split value -> j-dependent ~1e-3 score bias -> neighbor flips
// -> absmax 0.53. R8 (passing) computed norms from planes; this restores that.

constexpr int NB = 8;
constexpr int NP = 2048;
constexpr int KK = 20;

typedef short bf16x8 __attribute__((ext_vector_type(8)));
typedef float f32x16 __attribute__((ext_vector_type(16)));

__device__ __forceinline__ f32x16 MF(bf16x8 a, bf16x8 b, f32x16 c) {
  return __builtin_amdgcn_mfma_f32_32x32x16_bf16(a, b, c, 0, 0, 0);
}
__device__ __forceinline__ unsigned short bfh(float f) {
  return (unsigned short)(__float_as_uint(f) >> 16);  // truncating bf16
}
__device__ __forceinline__ float bff(unsigned short u) {
  return __uint_as_float(((unsigned)u) << 16);
}
__device__ __forceinline__ void split2(float v, unsigned short& h, unsigned short& l) {
  h = bfh(v); l = bfh(v - bff(h));
}
__device__ __forceinline__ void stage16(unsigned short* dst, const unsigned short* src) {
  *reinterpret_cast<uint4*>(dst) = *reinterpret_cast<const uint4*>(src);
}

#define FMA16(AV, BV, ACC)                                          \
  {                                                                 \
    const float _a[4] = {AV.x, AV.y, AV.z, AV.w};                   \
    const float _b[4] = {BV.x, BV.y, BV.z, BV.w};                   \
    _Pragma("unroll")                                               \
    for (int _e = 0; _e < 4; ++_e) {                                \
      _Pragma("unroll")                                             \
      for (int _f = 0; _f < 4; ++_f)                                \
        ACC[_e][_f] = fmaf(_a[_e], _b[_f], ACC[_e][_f]);            \
    }                                                               \
  }

// ---------------- pad x -> x4, plus L0 norms ----------------
__global__ __launch_bounds__(256) void pad_norms(const float* __restrict__ x,
    float* __restrict__ x4, float* __restrict__ nrm) {
  const int p = blockIdx.x * 256 + threadIdx.x;  // 16384
  float4 v;
  v.x = x[p * 3 + 0]; v.y = x[p * 3 + 1]; v.z = x[p * 3 + 2]; v.w = 0.f;
  *reinterpret_cast<float4*>(x4 + (size_t)p * 4) = v;
  nrm[p] = v.x * v.x + v.y * v.y + v.z * v.z;
}

// ---------------- all weight splits in one kernel ----------------
// wcat layout per conv layer: [hi: 2O*C][lo: 2O*C]; rows 0..O-1 = W1, O..2O-1 = W2-W1.
__global__ __launch_bounds__(256) void wsplit_all(const float* __restrict__ W1,
    const float* __restrict__ W2, const float* __restrict__ W3,
    const float* __restrict__ Wf,
    unsigned short* __restrict__ wb1, unsigned short* __restrict__ wb2,
    unsigned short* __restrict__ wb3,
    unsigned short* __restrict__ wfh, unsigned short* __restrict__ wfl) {
  const int id = blockIdx.x * 256 + threadIdx.x;  // 569344 total
  if (id < 524288) {
    unsigned short h, l;
    split2(Wf[id], h, l);
    wfh[id] = h; wfl[id] = l;
    return;
  }
  int id2 = id - 524288;
  const float* W; unsigned short* wb; int O, C;
  if (id2 < 4096)      { W = W1; wb = wb1; O = 64;  C = 64;  }
  else if (id2 < 12288){ W = W2; wb = wb2; O = 128; C = 64;  id2 -= 4096; }
  else                 { W = W3; wb = wb3; O = 256; C = 128; id2 -= 12288; }
  const int o = id2 / C, c = id2 % C;
  const float w1 = W[o * 2 * C + c];
  const float w2 = W[o * 2 * C + C + c];
  unsigned short h, l;
  split2(w1, h, l);
  wb[o * C + c] = h; wb[2 * O * C + o * C + c] = l;
  split2(w2 - w1, h, l);
  wb[(O + o) * C + c] = h; wb[2 * O * C + (O + o) * C + c] = l;
}

// ---------------- dist L0 (C=3, fp32 vector) ----------------
__global__ __launch_bounds__(256) void dist0_kernel(const float* __restrict__ X4,
    const float* __restrict__ norms, float* __restrict__ negd, int bbase) {
  __shared__ float sb[640];
  const int t = threadIdx.x, tr = t & 15, tcq = t >> 4;
  const int z = blockIdx.z, b = bbase + z;
  const int i0 = blockIdx.x * 64, j0 = blockIdx.y * 64;
  const int c4 = t >> 6, row = t & 63;
  if (t < 64) sb[512 + t] = norms[b * NP + i0 + t];
  else if (t < 128) sb[512 + t] = norms[b * NP + j0 + (t - 64)];
  sb[c4 * 64 + row] = X4[(size_t)(b * NP + i0 + row) * 4 + c4];
  sb[256 + c4 * 64 + row] = X4[(size_t)(b * NP + j0 + row) * 4 + c4];
  __syncthreads();
  float acc[4][4] = {};
#pragma unroll
  for (int c = 0; c < 4; ++c) {
    const float4 a = *reinterpret_cast<const float4*>(sb + c * 64 + tr * 4);
    const float4 bb = *reinterpret_cast<const float4*>(sb + 256 + c * 64 + tcq * 4);
    FMA16(a, bb, acc);
  }
#pragma unroll
  for (int e = 0; e < 4; ++e) {
    const int rowi = tr * 4 + e;
    const float ni = sb[512 + rowi];
    float4 nd;
    nd.x = 2.f * acc[e][0] - ni - sb[576 + tcq * 4 + 0];
    nd.y = 2.f * acc[e][1] - ni - sb[576 + tcq * 4 + 1];
    nd.z = 2.f * acc[e][2] - ni - sb[576 + tcq * 4 + 2];
    nd.w = 2.f * acc[e][3] - ni - sb[576 + tcq * 4 + 3];
    *reinterpret_cast<float4*>(negd + ((size_t)z * NP + i0 + rowi) * NP + j0 + tcq * 4) = nd;
  }
}

// ---------------- dist MFMA (l>=1): A in LDS, B frags from global ----------------
template<int C>
__global__ __launch_bounds__(256) void dist_mfma(const unsigned short* __restrict__ xh,
    const unsigned short* __restrict__ xl, int colbase,
    const float* __restrict__ norms, float* __restrict__ negd, int bbase) {
  constexpr int K8 = C / 8;
  constexpr int H = K8 / 2;
  __shared__ __align__(16) unsigned short sA[2 * K8 * 512];  // [plane][k8][r][8]
  __shared__ float fn[128];

  const int t = threadIdx.x, lane = t & 63, w = t >> 6;
  const int half = lane >> 5, l31 = lane & 31;
  const int rt = (w >> 1) * 32, tc = (w & 1) * 32;
  const int z = blockIdx.z, b = bbase + z;
  const int i0 = blockIdx.x * 64, j0 = blockIdx.y * 64;

  if (t < 64) fn[t] = norms[b * NP + i0 + t];
  else if (t < 128) fn[t] = norms[b * NP + j0 + (t - 64)];

#pragma unroll
  for (int i = 0; i < K8 / 2; ++i) {  // 2*K8*64 entries / 256 threads
    const int id = t + 256 * i;
    const int r = id & 63, k8 = (id >> 6) % K8, pl = id / (64 * K8);
    const unsigned short* src = (pl ? xl : xh) + ((size_t)(b * NP + i0 + r)) * 512 + colbase + k8 * 8;
    stage16(sA + ((pl * K8 + k8) * 64 + r) * 8, src);
  }

  const int col = tc + l31;
  const unsigned short* gbh = xh + ((size_t)(b * NP + j0 + col)) * 512 + colbase;
  const unsigned short* gbl = xl + ((size_t)(b * NP + j0 + col)) * 512 + colbase;
  bf16x8 BH[H], BL[H];
#pragma unroll
  for (int ch = 0; ch < H; ++ch) {
    const int k8 = ch * 2 + half;
    BH[ch] = *reinterpret_cast<const bf16x8*>(gbh + k8 * 8);
    BL[ch] = *reinterpret_cast<const bf16x8*>(gbl + k8 * 8);
  }
  __syncthreads();

  f32x16 acc;
#pragma unroll
  for (int i = 0; i < 16; ++i) acc[i] = 0.f;
#pragma unroll
  for (int ch = 0; ch < H; ++ch) {
    const int k8 = ch * 2 + half;
    const bf16x8 ah = *reinterpret_cast<const bf16x8*>(sA + ((0 * K8 + k8) * 64 + rt + l31) * 8);
    const bf16x8 al = *reinterpret_cast<const bf16x8*>(sA + ((1 * K8 + k8) * 64 + rt + l31) * 8);
    acc = MF(ah, BH[ch], acc); acc = MF(ah, BL[ch], acc); acc = MF(al, BH[ch], acc);
  }

  const float nj = fn[64 + col];
#pragma unroll
  for (int i = 0; i < 16; ++i) {
    const int row = rt + (i & 3) + 8 * (i >> 2) + 4 * half;
    negd[((size_t)z * NP + i0 + row) * NP + j0 + col] = 2.f * acc[i] - fn[row] - nj;
  }
}

// ---------------- knn select: one wave per row (R6) ----------------
__global__ __launch_bounds__(256) void knn_select_kernel(const float* __restrict__ negd,
    int* __restrict__ idxout, int bbase) {
  const int t = threadIdx.x, lane = t & 63, w = t >> 6;
  const int rloc = blockIdx.x * 4 + w;  // 0..8191 (4 batches)
  const float* rowp = negd + (size_t)rloc * NP + lane * 32;

  float v[32];
#pragma unroll
  for (int m = 0; m < 8; ++m) {
    const float4 d = *reinterpret_cast<const float4*>(rowp + m * 4);
    v[m * 4 + 0] = d.x; v[m * 4 + 1] = d.y; v[m * 4 + 2] = d.z; v[m * 4 + 3] = d.w;
  }
  float lm = v[0]; int lp = 0;
#pragma unroll
  for (int e = 1; e < 32; ++e)
    if (v[e] > lm) { lm = v[e]; lp = e; }

  int* op = idxout + (size_t)(bbase * NP + rloc) * KK;
  for (int r = 0; r < KK; ++r) {
    float wm = lm;
#pragma unroll
    for (int o = 1; o < 64; o <<= 1) wm = fmaxf(wm, __shfl_xor(wm, o));
    const unsigned long long bal = __ballot(lm == wm);
    const int wl = __ffsll(bal) - 1;
    if (lane == wl) {
      op[r] = lane * 32 + lp;
#pragma unroll
      for (int e = 0; e < 32; ++e)
        if (e == lp) v[e] = -__builtin_inff();
      lm = v[0]; lp = 0;
#pragma unroll
      for (int e = 1; e < 32; ++e)
        if (v[e] > lm) { lm = v[e]; lp = e; }
    }
  }
}

// ---------------- per-point GEMM, L0 (C=3, fp32 vector) ----------------
__global__ __launch_bounds__(256) void pt_gemm0(const float* __restrict__ x,
    const float* __restrict__ W, const float* __restrict__ bias,
    float* __restrict__ Y, float* __restrict__ T) {
  const int t = threadIdx.x;
  const int o = t & 63;
  const int g = blockIdx.x * 4 + (t >> 6);  // 0..16383
  const float x0 = x[(size_t)g * 3 + 0], x1 = x[(size_t)g * 3 + 1], x2 = x[(size_t)g * 3 + 2];
  const float w10 = W[o * 6 + 0], w11 = W[o * 6 + 1], w12 = W[o * 6 + 2];
  const float w20 = W[o * 6 + 3], w21 = W[o * 6 + 4], w22 = W[o * 6 + 5];
  Y[(size_t)g * 64 + o] = w10 * x0 + w11 * x1 + w12 * x2;
  T[(size_t)g * 64 + o] = (w20 - w10) * x0 + (w21 - w11) * x1 + (w22 - w12) * x2 + bias[o];
}

// ---------------- per-point GEMM (l>=1, MFMA, single phase): [Y||T] = X Wcat^T ----
template<int C, int O2>  // O2 = 2*O
__global__ __launch_bounds__(256) void pt_gemm(const unsigned short* __restrict__ xh,
    const unsigned short* __restrict__ xl, int colbase,
    const unsigned short* __restrict__ wch, const unsigned short* __restrict__ wcl,
    const float* __restrict__ bias, float* __restrict__ Y, float* __restrict__ T) {
  constexpr int K8 = C / 8;
  constexpr int H = K8 / 2;
  constexpr int O = O2 / 2;
  __shared__ __align__(16) unsigned short sA[2 * K8 * 512];

  const int t = threadIdx.x, lane = t & 63, w = t >> 6;
  const int half = lane >> 5, l31 = lane & 31;
  const int rt = (w >> 1) * 32, tc = (w & 1) * 32;
  const int n0 = blockIdx.x * 64, o0 = blockIdx.y * 64;
  const int col = o0 + tc + l31;

#pragma unroll
  for (int i = 0; i < K8 / 2; ++i) {
    const int id = t + 256 * i;
    const int r = id & 63, k8 = (id >> 6) % K8, pl = id / (64 * K8);
    const unsigned short* src = (pl ? xl : xh) + ((size_t)(n0 + r)) * 512 + colbase + k8 * 8;
    stage16(sA + ((pl * K8 + k8) * 64 + r) * 8, src);
  }

  const unsigned short* gbh = wch + (size_t)col * C;
  const unsigned short* gbl = wcl + (size_t)col * C;
  bf16x8 BH[H], BL[H];
#pragma unroll
  for (int ch = 0; ch < H; ++ch) {
    const int k8 = ch * 2 + half;
    BH[ch] = *reinterpret_cast<const bf16x8*>(gbh + k8 * 8);
    BL[ch] = *reinterpret_cast<const bf16x8*>(gbl + k8 * 8);
  }
  __syncthreads();

  f32x16 acc;
#pragma unroll
  for (int i = 0; i < 16; ++i) acc[i] = 0.f;
#pragma unroll
  for (int ch = 0; ch < H; ++ch) {
    const int k8 = ch * 2 + half;
    const bf16x8 ah = *reinterpret_cast<const bf16x8*>(sA + ((0 * K8 + k8) * 64 + rt + l31) * 8);
    const bf16x8 al = *reinterpret_cast<const bf16x8*>(sA + ((1 * K8 + k8) * 64 + rt + l31) * 8);
    acc = MF(ah, BH[ch], acc); acc = MF(ah, BL[ch], acc); acc = MF(al, BH[ch], acc);
  }

  if (col < O) {
#pragma unroll
    for (int i = 0; i < 16; ++i) {
      const int row = n0 + rt + (i & 3) + 8 * (i >> 2) + 4 * half;
      Y[(size_t)row * O + col] = acc[i];
    }
  } else {
    const float bv = bias[col - O];
#pragma unroll
    for (int i = 0; i < 16; ++i) {
      const int row = n0 + rt + (i & 3) + 8 * (i >> 2) + 4 * half;
      T[(size_t)row * O + (col - O)] = acc[i] + bv;
    }
  }
}

// ---------------- edge reduce: max/sum/sumsq over gathered Y rows ----------------
template<int O>
__global__ __launch_bounds__(256) void edge_reduce(const float* __restrict__ Y,
    const float* __restrict__ T, const int* __restrict__ idx,
    float* __restrict__ outmax, float* __restrict__ ssum, float* __restrict__ ssq) {
  constexpr int PTS = 32;
  constexpr int NG = 256 / O;
  const int t = threadIdx.x;
  const int o = t % O, ng = t / O;
  const int g0 = blockIdx.x * PTS;
  float sacc = 0.f, qacc = 0.f;
  for (int p = ng; p < PTS; p += NG) {
    const int g = g0 + p;
    const int b = g >> 11;
    const float tv = T[(size_t)g * O + o];
    const int* ip = idx + (size_t)g * KK;
    int ji[KK];
#pragma unroll
    for (int k = 0; k < KK; ++k) ji[k] = ip[k];
    float vs[KK];
#pragma unroll
    for (int k = 0; k < KK; ++k) vs[k] = Y[(size_t)(b * NP + ji[k]) * O + o];
    float mx = -__builtin_inff();
#pragma unroll
    for (int k = 0; k < KK; ++k) {
      const float h = vs[k] + tv;
      mx = fmaxf(mx, h);
      sacc += h;
      qacc = fmaf(h, h, qacc);
    }
    outmax[(size_t)g * O + o] = mx;
  }
  atomicAdd(ssum + o, sacc);
  atomicAdd(ssq + o, qacc);
}

// ---------------- bn + leaky relu -> bf16 planes (+fused next-layer norms) ------
// Norm accumulates the RECONSTRUCTED value (hi+lo) so it is exactly consistent
// with the planes dist_mfma multiplies (R9's fp32-val norm flipped neighbors).
template<int O, bool WN>
__global__ __launch_bounds__(256) void bnrelu_kernel(const float* __restrict__ fA,
    const float* __restrict__ ssum, const float* __restrict__ ssq,
    const float* __restrict__ g, const float* __restrict__ be,
    unsigned short* __restrict__ xh, unsigned short* __restrict__ xl, int colbase,
    float* __restrict__ nrm) {
  constexpr float INV = 1.0f / 327680.0f;  // B*N*K
  const int t4 = blockIdx.x * 256 + threadIdx.x;
  const int e0 = t4 * 4;
  const int r = e0 / O, c = e0 % O;
  const float4 h1 = *reinterpret_cast<const float4*>(fA + (size_t)r * O + c);
  float hv[4] = {h1.x, h1.y, h1.z, h1.w};
  unsigned short hh[4], ll[4];
  float s = 0.f;
#pragma unroll
  for (int j = 0; j < 4; ++j) {
    const int col = c + j;
    const float m = ssum[col] * INV;
    const float v = ssq[col] * INV - m * m;
    const float sc = g[col] / sqrtf(v + 1e-5f);
    float val = (hv[j] - m) * sc + be[col];
    val = (val >= 0.f) ? val : 0.2f * val;
    split2(val, hh[j], ll[j]);
    const float recon = bff(hh[j]) + bff(ll[j]);
    s = fmaf(recon, recon, s);
  }
  const size_t ob = (size_t)r * 512 + colbase + c;
  uint2 ph, pl;
  ph.x = (unsigned)hh[0] | ((unsigned)hh[1] << 16);
  ph.y = (unsigned)hh[2] | ((unsigned)hh[3] << 16);
  pl.x = (unsigned)ll[0] | ((unsigned)ll[1] << 16);
  pl.y = (unsigned)ll[2] | ((unsigned)ll[3] << 16);
  *reinterpret_cast<uint2*>(xh + ob) = ph;
  *reinterpret_cast<uint2*>(xl + ob) = pl;
  if (WN) atomicAdd(nrm + r, s);
}

// ---------------- final conv + global max pool: A in LDS (chunk=128), B in regs --
__global__ __launch_bounds__(256) void final_mfma(const unsigned short* __restrict__ xh,
    const unsigned short* __restrict__ xl, const unsigned short* __restrict__ wfh,
    const unsigned short* __restrict__ wfl, unsigned* __restrict__ outenc) {
  __shared__ __align__(16) unsigned short sA[2 * 16 * 512];  // 32 KB
  __shared__ float fr[128];
  const int t = threadIdx.x, lane = t & 63, w = t >> 6;
  const int half = lane >> 5, l31 = lane & 31;
  const int rt = (w >> 1) * 32, tc = (w & 1) * 32;
  const int b = blockIdx.z, n0 = blockIdx.x * 64, o0 = blockIdx.y * 64;
  const int col = o0 + tc + l31;
  const unsigned short* gbh = wfh + (size_t)col * 512;
  const unsigned short* gbl = wfl + (size_t)col * 512;

  f32x16 acc;
#pragma unroll
  for (int i = 0; i < 16; ++i) acc[i] = 0.f;

  for (int cc = 0; cc < 4; ++cc) {  // 128 channels per chunk
    bf16x8 BH[8], BL[8];
#pragma unroll
    for (int ch = 0; ch < 8; ++ch) {
      const int k8 = ch * 2 + half;
      BH[ch] = *reinterpret_cast<const bf16x8*>(gbh + cc * 128 + k8 * 8);
      BL[ch] = *reinterpret_cast<const bf16x8*>(gbl + cc * 128 + k8 * 8);
    }
    __syncthreads();  // protect previous chunk's LDS reads
#pragma unroll
    for (int i = 0; i < 8; ++i) {  // 2048 entries / 256 threads
      const int id = t + 256 * i;
      const int r = id & 63, k8 = (id >> 6) & 15, pl = id >> 10;
      const unsigned short* src = (pl ? xl : xh) + ((size_t)(b * NP + n0 + r)) * 512 + cc * 128 + k8 * 8;
      stage16(sA + ((pl * 16 + k8) * 64 + r) * 8, src);
    }
    __syncthreads();
#pragma unroll
    for (int ch = 0; ch < 8; ++ch) {
      const int k8 = ch * 2 + half;
      const bf16x8 ah = *reinterpret_cast<const bf16x8*>(sA + ((0 * 16 + k8) * 64 + rt + l31) * 8);
      const bf16x8 al = *reinterpret_cast<const bf16x8*>(sA + ((1 * 16 + k8) * 64 + rt + l31) * 8);
      acc = MF(ah, BH[ch], acc); acc = MF(ah, BL[ch], acc); acc = MF(al, BH[ch], acc);
    }
  }

  float M = acc[0];
#pragma unroll
  for (int i = 1; i < 16; ++i) M = fmaxf(M, acc[i]);
  M = fmaxf(M, __shfl_xor(M, 32));
  fr[w * 32 + l31] = M;
  __syncthreads();
  if (t < 64) {
    const float Mc = fmaxf(fr[t], fr[64 + t]);
    const unsigned ub = __float_as_uint(Mc);
    const unsigned key = (ub & 0x80000000u) ? ~ub : (ub | 0x80000000u);
    atomicMax(outenc + b * 1024 + o0 + t, key);
  }
}

__global__ __launch_bounds__(256) void decode_kernel(const unsigned int* __restrict__ enc,
    const float* __restrict__ bf, float* __restrict__ out) {
  const int gid = blockIdx.x * 256 + threadIdx.x;  // 8192
  const unsigned key = enc[gid];
  const unsigned ubits = (key & 0x80000000u) ? (key & 0x7fffffffu) : ~key;
  out[gid] = __uint_as_float(ubits) + bf[gid & 1023];
}

// ---------------- launch ----------------
extern "C" void kernel_launch(void* const* d_in, const int* in_sizes, int n_in,
                              void* d_out, int out_size, void* d_ws, size_t ws_size,
                              hipStream_t stream) {
  (void)in_sizes; (void)n_in; (void)out_size; (void)ws_size;
  const float* x   = (const float*)d_in[0];
  const float* W0  = (const float*)d_in[1];
  const float* b0  = (const float*)d_in[2];
  const float* g0  = (const float*)d_in[3];
  const float* be0 = (const float*)d_in[4];
  const float* W1  = (const float*)d_in[5];
  const float* b1  = (const float*)d_in[6];
  const float* g1  = (const float*)d_in[7];
  const float* be1 = (const float*)d_in[8];
  const float* W2  = (const float*)d_in[9];
  const float* b2  = (const float*)d_in[10];
  const float* g2  = (const float*)d_in[11];
  const float* be2 = (const float*)d_in[12];
  const float* W3  = (const float*)d_in[13];
  const float* b3  = (const float*)d_in[14];
  const float* g3  = (const float*)d_in[15];
  const float* be3 = (const float*)d_in[16];
  const float* Wf  = (const float*)d_in[17];
  const float* bf  = (const float*)d_in[18];

  float* wsf = (float*)d_ws;
  int* idxb = (int*)d_ws;                        // 327,680 ints
  float* stats = wsf + 327680;                   // 2048 (4 layers x sum|sq x 256)
  float* nb = wsf + 329728;                      // 4 x 16384 norm buffers
  unsigned* outenc = (unsigned*)(wsf + 395264);  // 8192
  float* x4 = wsf + 403456;                      // 65536
  float* featA = wsf + 468992;                   // 16384*256
  float* negd = wsf + 4663296;                   // 4*2048*2048 (67 MB)
  float* Yb = negd;                              // alias (disjoint phases)
  float* Tb = negd + 4194304;
  unsigned short* xh = (unsigned short*)(wsf + 21440512);  // [16384][512]
  unsigned short* xl = xh + 8388608;
  unsigned short* wb1 = xl + 8388608;            // 2*(2*64*64)   = 16384
  unsigned short* wb2 = wb1 + 16384;             // 2*(2*128*64)  = 32768
  unsigned short* wb3 = wb2 + 32768;             // 2*(2*256*128) = 131072
  unsigned short* wfh = wb3 + 131072;            // 1024*512
  unsigned short* wfl = wfh + 524288;

  float* normsA = nb, *normsB = nb + 16384, *normsC = nb + 32768, *normsD = nb + 49152;

  hipMemsetAsync(stats, 0, (2048 + 65536) * sizeof(float), stream);  // stats + norm bufs
  hipMemsetAsync(outenc, 0, 8192 * sizeof(unsigned), stream);

  const dim3 blk(256, 1, 1);
  const dim3 ggrid(32, 32, 4);
  const dim3 sgrid(2048, 1, 1);
  const dim3 ergrid(512, 1, 1);

  pad_norms<<<dim3(64), blk, 0, stream>>>(x, x4, normsA);
  wsplit_all<<<dim3(2224), blk, 0, stream>>>(W1, W2, W3, Wf, wb1, wb2, wb3, wfh, wfl);

  // Layer 0 (C=3 -> 64, out cols [0,64))
  for (int cb = 0; cb < 2; ++cb) {
    dist0_kernel<<<ggrid, blk, 0, stream>>>(x4, normsA, negd, 4 * cb);
    knn_select_kernel<<<sgrid, blk, 0, stream>>>(negd, idxb, 4 * cb);
  }
  pt_gemm0<<<dim3(4096), blk, 0, stream>>>(x, W0, b0, Yb, Tb);
  edge_reduce<64><<<ergrid, blk, 0, stream>>>(Yb, Tb, idxb, featA, stats, stats + 256);
  bnrelu_kernel<64, true><<<dim3(1024), blk, 0, stream>>>(featA, stats, stats + 256,
      g0, be0, xh, xl, 0, normsB);

  // Layer 1 (64 -> 64, in cols [0,64), out [64,128))
  for (int cb = 0; cb < 2; ++cb) {
    dist_mfma<64><<<ggrid, blk, 0, stream>>>(xh, xl, 0, normsB, negd, 4 * cb);
    knn_select_kernel<<<sgrid, blk, 0, stream>>>(negd, idxb, 4 * cb);
  }
  pt_gemm<64, 128><<<dim3(256, 2), blk, 0, stream>>>(xh, xl, 0, wb1, wb1 + 8192, b1, Yb, Tb);
  edge_reduce<64><<<ergrid, blk, 0, stream>>>(Yb, Tb, idxb, featA, stats + 512, stats + 768);
  bnrelu_kernel<64, true><<<dim3(1024), blk, 0, stream>>>(featA, stats + 512, stats + 768,
      g1, be1, xh, xl, 64, normsC);

  // Layer 2 (64 -> 128, in cols [64,128), out [128,256))
  for (int cb = 0; cb < 2; ++cb) {
    dist_mfma<64><<<ggrid, blk, 0, stream>>>(xh, xl, 64, normsC, negd, 4 * cb);
    knn_select_kernel<<<sgrid, blk, 0, stream>>>(negd, idxb, 4 * cb);
  }
  pt_gemm<64, 256><<<dim3(256, 4), blk, 0, stream>>>(xh, xl, 64, wb2, wb2 + 16384, b2, Yb, Tb);
  edge_reduce<128><<<ergrid, blk, 0, stream>>>(Yb, Tb, idxb, featA, stats + 1024, stats + 1280);
  bnrelu_kernel<128, true><<<dim3(2048), blk, 0, stream>>>(featA, stats + 1024, stats + 1280,
      g2, be2, xh, xl, 128, normsD);

  // Layer 3 (128 -> 256, in cols [128,256), out [256,512))
  for (int cb = 0; cb < 2; ++cb) {
    dist_mfma<128><<<ggrid, blk, 0, stream>>>(xh, xl, 128, normsD, negd, 4 * cb);
    knn_select_kernel<<<sgrid, blk, 0, stream>>>(negd, idxb, 4 * cb);
  }
  pt_gemm<128, 512><<<dim3(256, 8), blk, 0, stream>>>(xh, xl, 128, wb3, wb3 + 65536, b3, Yb, Tb);
  edge_reduce<256><<<ergrid, blk, 0, stream>>>(Yb, Tb, idxb, featA, stats + 1536, stats + 1792);
  bnrelu_kernel<256, false><<<dim3(4096), blk, 0, stream>>>(featA, stats + 1536, stats + 1792,
      g3, be3, xh, xl, 256, nullptr);

  // Final 1x1 conv + global max pool
  final_mfma<<<dim3(32, 16, 8), blk, 0, stream>>>(xh, xl, wfh, wfl, outenc);
  decode_kernel<<<dim3(32), blk, 0, stream>>>(outenc, bf, (float*)d_out);
}

// Round 11
// 1026.720 us; speedup vs baseline: 1.4228x; 1.2934x over previous
//
#include <hip/hip_runtime.h>
#include <cstdint>
#include <cstddef>

// DGCNN forward. R11: fragment-order storage.
// Features stored as xT[tile=n>>6][k8=c>>3][r=n&63][8] (hi/lo bf16 planes);
// weights pre-transposed to the same order. MFMA A/B fragments then load
// DIRECTLY from global, contiguous 512B per half-wave -> dist/pt_gemm are
// LDS-free & barrier-free; final keeps LDS only for the max-reduce.
// (R10's row-major layout made every fragment/staging load a 64-line gather:
// final_mfma MfmaUtil 10.5%, VALUBusy 4% = pure gather-latency stall.)

constexpr int NB = 8;
constexpr int NP = 2048;
constexpr int KK = 20;

typedef short bf16x8 __attribute__((ext_vector_type(8)));
typedef float f32x16 __attribute__((ext_vector_type(16)));

__device__ __forceinline__ f32x16 MF(bf16x8 a, bf16x8 b, f32x16 c) {
  return __builtin_amdgcn_mfma_f32_32x32x16_bf16(a, b, c, 0, 0, 0);
}
__device__ __forceinline__ unsigned short bfh(float f) {
  return (unsigned short)(__float_as_uint(f) >> 16);  // truncating bf16
}
__device__ __forceinline__ float bff(unsigned short u) {
  return __uint_as_float(((unsigned)u) << 16);
}
__device__ __forceinline__ void split2(float v, unsigned short& h, unsigned short& l) {
  h = bfh(v); l = bfh(v - bff(h));
}

#define FMA16(AV, BV, ACC)                                          \
  {                                                                 \
    const float _a[4] = {AV.x, AV.y, AV.z, AV.w};                   \
    const float _b[4] = {BV.x, BV.y, BV.z, BV.w};                   \
    _Pragma("unroll")                                               \
    for (int _e = 0; _e < 4; ++_e) {                                \
      _Pragma("unroll")                                             \
      for (int _f = 0; _f < 4; ++_f)                                \
        ACC[_e][_f] = fmaf(_a[_e], _b[_f], ACC[_e][_f]);            \
    }                                                               \
  }

// ---------------- pad x -> x4, plus L0 norms ----------------
__global__ __launch_bounds__(256) void pad_norms(const float* __restrict__ x,
    float* __restrict__ x4, float* __restrict__ nrm) {
  const int p = blockIdx.x * 256 + threadIdx.x;  // 16384
  float4 v;
  v.x = x[p * 3 + 0]; v.y = x[p * 3 + 1]; v.z = x[p * 3 + 2]; v.w = 0.f;
  *reinterpret_cast<float4*>(x4 + (size_t)p * 4) = v;
  nrm[p] = v.x * v.x + v.y * v.y + v.z * v.z;
}

// ---------------- all weight splits, fragment-order output ----------------
// conv wb layout: hi plane [(row>>6)*K8 + k8][r=row&63][8], rows 0..O-1 = W1,
// O..2O-1 = W2-W1; lo plane at +2*O*C. wfT same with K8=64.
__global__ __launch_bounds__(256) void wsplit_all(const float* __restrict__ W1,
    const float* __restrict__ W2, const float* __restrict__ W3,
    const float* __restrict__ Wf,
    unsigned short* __restrict__ wb1, unsigned short* __restrict__ wb2,
    unsigned short* __restrict__ wb3,
    unsigned short* __restrict__ wfh, unsigned short* __restrict__ wfl) {
  const int id = blockIdx.x * 256 + threadIdx.x;  // 569344 total
  if (id < 524288) {
    const int row = id >> 9, c = id & 511;
    unsigned short h, l;
    split2(Wf[id], h, l);
    const size_t a = ((((size_t)(row >> 6)) * 64 + (c >> 3)) * 64 + (row & 63)) * 8 + (c & 7);
    wfh[a] = h; wfl[a] = l;
    return;
  }
  int id2 = id - 524288;
  const float* W; unsigned short* wb; int O, C;
  if (id2 < 4096)      { W = W1; wb = wb1; O = 64;  C = 64;  }
  else if (id2 < 12288){ W = W2; wb = wb2; O = 128; C = 64;  id2 -= 4096; }
  else                 { W = W3; wb = wb3; O = 256; C = 128; id2 -= 12288; }
  const int o = id2 / C, c = id2 % C;
  const int K8 = C >> 3;
  const float w1 = W[o * 2 * C + c];
  const float w2 = W[o * 2 * C + C + c];
  unsigned short h, l;
  const int r1 = o, rd = O + o;
  const size_t a1 = (((size_t)(r1 >> 6) * K8 + (c >> 3)) * 64 + (r1 & 63)) * 8 + (c & 7);
  const size_t ad = (((size_t)(rd >> 6) * K8 + (c >> 3)) * 64 + (rd & 63)) * 8 + (c & 7);
  split2(w1, h, l);
  wb[a1] = h; wb[2 * O * C + a1] = l;
  split2(w2 - w1, h, l);
  wb[ad] = h; wb[2 * O * C + ad] = l;
}

// ---------------- dist L0 (C=3, fp32 vector) ----------------
__global__ __launch_bounds__(256) void dist0_kernel(const float* __restrict__ X4,
    const float* __restrict__ norms, float* __restrict__ negd, int bbase) {
  __shared__ float sb[640];
  const int t = threadIdx.x, tr = t & 15, tcq = t >> 4;
  const int z = blockIdx.z, b = bbase + z;
  const int i0 = blockIdx.x * 64, j0 = blockIdx.y * 64;
  const int c4 = t >> 6, row = t & 63;
  if (t < 64) sb[512 + t] = norms[b * NP + i0 + t];
  else if (t < 128) sb[512 + t] = norms[b * NP + j0 + (t - 64)];
  sb[c4 * 64 + row] = X4[(size_t)(b * NP + i0 + row) * 4 + c4];
  sb[256 + c4 * 64 + row] = X4[(size_t)(b * NP + j0 + row) * 4 + c4];
  __syncthreads();
  float acc[4][4] = {};
#pragma unroll
  for (int c = 0; c < 4; ++c) {
    const float4 a = *reinterpret_cast<const float4*>(sb + c * 64 + tr * 4);
    const float4 bb = *reinterpret_cast<const float4*>(sb + 256 + c * 64 + tcq * 4);
    FMA16(a, bb, acc);
  }
#pragma unroll
  for (int e = 0; e < 4; ++e) {
    const int rowi = tr * 4 + e;
    const float ni = sb[512 + rowi];
    float4 nd;
    nd.x = 2.f * acc[e][0] - ni - sb[576 + tcq * 4 + 0];
    nd.y = 2.f * acc[e][1] - ni - sb[576 + tcq * 4 + 1];
    nd.z = 2.f * acc[e][2] - ni - sb[576 + tcq * 4 + 2];
    nd.w = 2.f * acc[e][3] - ni - sb[576 + tcq * 4 + 3];
    *reinterpret_cast<float4*>(negd + ((size_t)z * NP + i0 + rowi) * NP + j0 + tcq * 4) = nd;
  }
}

// ---------------- dist MFMA (l>=1): LDS-free, frags direct from xT ----------------
template<int C>
__global__ __launch_bounds__(256) void dist_mfma(const unsigned short* __restrict__ xh,
    const unsigned short* __restrict__ xl, int colbase,
    const float* __restrict__ norms, float* __restrict__ negd, int bbase) {
  constexpr int H = C / 16;
  const int t = threadIdx.x, lane = t & 63, w = t >> 6;
  const int half = lane >> 5, l31 = lane & 31;
  const int rt = (w >> 1) * 32, tc = (w & 1) * 32;
  const int z = blockIdx.z, b = bbase + z;
  const int i0 = blockIdx.x * 64, j0 = blockIdx.y * 64;
  const int ti = (b * NP + i0) >> 6, tj = (b * NP + j0) >> 6;
  const int k8b = colbase >> 3;
  const int col = tc + l31;

  bf16x8 BH[H], BL[H];
#pragma unroll
  for (int ch = 0; ch < H; ++ch) {
    const size_t a = (((size_t)tj * 64 + k8b + ch * 2 + half) * 64 + col) * 8;
    BH[ch] = *reinterpret_cast<const bf16x8*>(xh + a);
    BL[ch] = *reinterpret_cast<const bf16x8*>(xl + a);
  }

  f32x16 acc;
#pragma unroll
  for (int i = 0; i < 16; ++i) acc[i] = 0.f;
#pragma unroll
  for (int ch = 0; ch < H; ++ch) {
    const size_t a = (((size_t)ti * 64 + k8b + ch * 2 + half) * 64 + rt + l31) * 8;
    const bf16x8 ah = *reinterpret_cast<const bf16x8*>(xh + a);
    const bf16x8 al = *reinterpret_cast<const bf16x8*>(xl + a);
    acc = MF(ah, BH[ch], acc); acc = MF(ah, BL[ch], acc); acc = MF(al, BH[ch], acc);
  }

  const float nj = norms[b * NP + j0 + col];
#pragma unroll
  for (int i = 0; i < 16; ++i) {
    const int row = rt + (i & 3) + 8 * (i >> 2) + 4 * half;
    const float ni = norms[b * NP + i0 + row];
    negd[((size_t)z * NP + i0 + row) * NP + j0 + col] = 2.f * acc[i] - ni - nj;
  }
}

// ---------------- knn select: one wave per row ----------------
__global__ __launch_bounds__(256) void knn_select_kernel(const float* __restrict__ negd,
    int* __restrict__ idxout, int bbase) {
  const int t = threadIdx.x, lane = t & 63, w = t >> 6;
  const int rloc = blockIdx.x * 4 + w;  // 0..8191 (4 batches)
  const float* rowp = negd + (size_t)rloc * NP + lane * 32;

  float v[32];
#pragma unroll
  for (int m = 0; m < 8; ++m) {
    const float4 d = *reinterpret_cast<const float4*>(rowp + m * 4);
    v[m * 4 + 0] = d.x; v[m * 4 + 1] = d.y; v[m * 4 + 2] = d.z; v[m * 4 + 3] = d.w;
  }
  float lm = v[0]; int lp = 0;
#pragma unroll
  for (int e = 1; e < 32; ++e)
    if (v[e] > lm) { lm = v[e]; lp = e; }

  int* op = idxout + (size_t)(bbase * NP + rloc) * KK;
  for (int r = 0; r < KK; ++r) {
    float wm = lm;
#pragma unroll
    for (int o = 1; o < 64; o <<= 1) wm = fmaxf(wm, __shfl_xor(wm, o));
    const unsigned long long bal = __ballot(lm == wm);
    const int wl = __ffsll(bal) - 1;
    if (lane == wl) {
      op[r] = lane * 32 + lp;
#pragma unroll
      for (int e = 0; e < 32; ++e)
        if (e == lp) v[e] = -__builtin_inff();
      lm = v[0]; lp = 0;
#pragma unroll
      for (int e = 1; e < 32; ++e)
        if (v[e] > lm) { lm = v[e]; lp = e; }
    }
  }
}

// ---------------- per-point GEMM, L0 (C=3, fp32 vector) ----------------
__global__ __launch_bounds__(256) void pt_gemm0(const float* __restrict__ x,
    const float* __restrict__ W, const float* __restrict__ bias,
    float* __restrict__ Y, float* __restrict__ T) {
  const int t = threadIdx.x;
  const int o = t & 63;
  const int g = blockIdx.x * 4 + (t >> 6);  // 0..16383
  const float x0 = x[(size_t)g * 3 + 0], x1 = x[(size_t)g * 3 + 1], x2 = x[(size_t)g * 3 + 2];
  const float w10 = W[o * 6 + 0], w11 = W[o * 6 + 1], w12 = W[o * 6 + 2];
  const float w20 = W[o * 6 + 3], w21 = W[o * 6 + 4], w22 = W[o * 6 + 5];
  Y[(size_t)g * 64 + o] = w10 * x0 + w11 * x1 + w12 * x2;
  T[(size_t)g * 64 + o] = (w20 - w10) * x0 + (w21 - w11) * x1 + (w22 - w12) * x2 + bias[o];
}

// ---------------- per-point GEMM (l>=1): LDS-free, [Y||T] = X Wcat^T ----------------
template<int C, int O2>  // O2 = 2*O
__global__ __launch_bounds__(256) void pt_gemm(const unsigned short* __restrict__ xh,
    const unsigned short* __restrict__ xl, int colbase,
    const unsigned short* __restrict__ wch, const unsigned short* __restrict__ wcl,
    const float* __restrict__ bias, float* __restrict__ Y, float* __restrict__ T) {
  constexpr int K8 = C / 8;
  constexpr int H = K8 / 2;
  constexpr int O = O2 / 2;
  const int t = threadIdx.x, lane = t & 63, w = t >> 6;
  const int half = lane >> 5, l31 = lane & 31;
  const int rt = (w >> 1) * 32, tc = (w & 1) * 32;
  const int n0 = blockIdx.x * 64, o0 = blockIdx.y * 64;
  const int tn = n0 >> 6, to = o0 >> 6;
  const int k8b = colbase >> 3;
  const int col = o0 + tc + l31;

  bf16x8 BH[H], BL[H];
#pragma unroll
  for (int ch = 0; ch < H; ++ch) {
    const size_t a = (((size_t)to * K8 + ch * 2 + half) * 64 + tc + l31) * 8;
    BH[ch] = *reinterpret_cast<const bf16x8*>(wch + a);
    BL[ch] = *reinterpret_cast<const bf16x8*>(wcl + a);
  }

  f32x16 acc;
#pragma unroll
  for (int i = 0; i < 16; ++i) acc[i] = 0.f;
#pragma unroll
  for (int ch = 0; ch < H; ++ch) {
    const size_t a = (((size_t)tn * 64 + k8b + ch * 2 + half) * 64 + rt + l31) * 8;
    const bf16x8 ah = *reinterpret_cast<const bf16x8*>(xh + a);
    const bf16x8 al = *reinterpret_cast<const bf16x8*>(xl + a);
    acc = MF(ah, BH[ch], acc); acc = MF(ah, BL[ch], acc); acc = MF(al, BH[ch], acc);
  }

  if (col < O) {
#pragma unroll
    for (int i = 0; i < 16; ++i) {
      const int row = n0 + rt + (i & 3) + 8 * (i >> 2) + 4 * half;
      Y[(size_t)row * O + col] = acc[i];
    }
  } else {
    const float bv = bias[col - O];
#pragma unroll
    for (int i = 0; i < 16; ++i) {
      const int row = n0 + rt + (i & 3) + 8 * (i >> 2) + 4 * half;
      T[(size_t)row * O + (col - O)] = acc[i] + bv;
    }
  }
}

// ---------------- edge reduce: max/sum/sumsq over gathered Y rows ----------------
template<int O>
__global__ __launch_bounds__(256) void edge_reduce(const float* __restrict__ Y,
    const float* __restrict__ T, const int* __restrict__ idx,
    float* __restrict__ outmax, float* __restrict__ ssum, float* __restrict__ ssq) {
  constexpr int PTS = 32;
  constexpr int NG = 256 / O;
  const int t = threadIdx.x;
  const int o = t % O, ng = t / O;
  const int g0 = blockIdx.x * PTS;
  float sacc = 0.f, qacc = 0.f;
  for (int p = ng; p < PTS; p += NG) {
    const int g = g0 + p;
    const int b = g >> 11;
    const float tv = T[(size_t)g * O + o];
    const int* ip = idx + (size_t)g * KK;
    int ji[KK];
#pragma unroll
    for (int k = 0; k < KK; ++k) ji[k] = ip[k];
    float vs[KK];
#pragma unroll
    for (int k = 0; k < KK; ++k) vs[k] = Y[(size_t)(b * NP + ji[k]) * O + o];
    float mx = -__builtin_inff();
#pragma unroll
    for (int k = 0; k < KK; ++k) {
      const float h = vs[k] + tv;
      mx = fmaxf(mx, h);
      sacc += h;
      qacc = fmaf(h, h, qacc);
    }
    outmax[(size_t)g * O + o] = mx;
  }
  atomicAdd(ssum + o, sacc);
  atomicAdd(ssq + o, qacc);
}

// ---------------- bn + leaky relu -> fragment-order bf16 planes ----------------
// Work item = (tile, k8loc, r): one thread produces 8 consecutive channels of one
// row -> one 16B write per plane, contiguous across the wave (r fastest). BN
// params are wave-uniform (same k8loc across wave). Norm uses RECONSTRUCTED vals.
template<int O, bool WN>
__global__ __launch_bounds__(256) void bnrelu_kernel(const float* __restrict__ fA,
    const float* __restrict__ ssum, const float* __restrict__ ssq,
    const float* __restrict__ g, const float* __restrict__ be,
    unsigned short* __restrict__ xh, unsigned short* __restrict__ xl, int colbase,
    float* __restrict__ nrm) {
  constexpr float INV = 1.0f / 327680.0f;  // B*N*K
  constexpr int K8 = O / 8;
  const int id = blockIdx.x * 256 + threadIdx.x;  // 16384*K8 items
  const int r = id & 63;
  const int k8loc = (id >> 6) % K8;
  const int tile = (id >> 6) / K8;
  const int n = tile * 64 + r;
  const int c0 = k8loc * 8;

  float hv[8];
  {
    const float4 p0 = *reinterpret_cast<const float4*>(fA + (size_t)n * O + c0);
    const float4 p1 = *reinterpret_cast<const float4*>(fA + (size_t)n * O + c0 + 4);
    hv[0] = p0.x; hv[1] = p0.y; hv[2] = p0.z; hv[3] = p0.w;
    hv[4] = p1.x; hv[5] = p1.y; hv[6] = p1.z; hv[7] = p1.w;
  }
  unsigned short hh[8], ll[8];
  float s = 0.f;
#pragma unroll
  for (int j = 0; j < 8; ++j) {
    const int col = c0 + j;
    const float m = ssum[col] * INV;
    const float v = ssq[col] * INV - m * m;
    const float sc = g[col] / sqrtf(v + 1e-5f);
    float val = (hv[j] - m) * sc + be[col];
    val = (val >= 0.f) ? val : 0.2f * val;
    split2(val, hh[j], ll[j]);
    const float recon = bff(hh[j]) + bff(ll[j]);
    s = fmaf(recon, recon, s);
  }
  const size_t ob = (((size_t)tile * 64 + (colbase >> 3) + k8loc) * 64 + r) * 8;
  uint4 ph, pl;
  ph.x = (unsigned)hh[0] | ((unsigned)hh[1] << 16);
  ph.y = (unsigned)hh[2] | ((unsigned)hh[3] << 16);
  ph.z = (unsigned)hh[4] | ((unsigned)hh[5] << 16);
  ph.w = (unsigned)hh[6] | ((unsigned)hh[7] << 16);
  pl.x = (unsigned)ll[0] | ((unsigned)ll[1] << 16);
  pl.y = (unsigned)ll[2] | ((unsigned)ll[3] << 16);
  pl.z = (unsigned)ll[4] | ((unsigned)ll[5] << 16);
  pl.w = (unsigned)ll[6] | ((unsigned)ll[7] << 16);
  *reinterpret_cast<uint4*>(xh + ob) = ph;
  *reinterpret_cast<uint4*>(xl + ob) = pl;
  if (WN) atomicAdd(nrm + n, s);
}

// ---------------- final conv + global max pool: frags direct from xT/wfT ----------
__global__ __launch_bounds__(256) void final_mfma(const unsigned short* __restrict__ xh,
    const unsigned short* __restrict__ xl, const unsigned short* __restrict__ wfh,
    const unsigned short* __restrict__ wfl, unsigned* __restrict__ outenc) {
  __shared__ float fr[128];
  const int t = threadIdx.x, lane = t & 63, w = t >> 6;
  const int half = lane >> 5, l31 = lane & 31;
  const int rt = (w >> 1) * 32, tc = (w & 1) * 32;
  const int b = blockIdx.z, n0 = blockIdx.x * 64, o0 = blockIdx.y * 64;
  const int tn = (b * NP + n0) >> 6, to = o0 >> 6;

  f32x16 acc;
#pragma unroll
  for (int i = 0; i < 16; ++i) acc[i] = 0.f;

  for (int cc = 0; cc < 4; ++cc) {  // 128 channels per chunk
    bf16x8 BH[8], BL[8];
#pragma unroll
    for (int ch = 0; ch < 8; ++ch) {
      const int k8 = cc * 16 + ch * 2 + half;
      const size_t a = (((size_t)to * 64 + k8) * 64 + tc + l31) * 8;
      BH[ch] = *reinterpret_cast<const bf16x8*>(wfh + a);
      BL[ch] = *reinterpret_cast<const bf16x8*>(wfl + a);
    }
#pragma unroll
    for (int ch = 0; ch < 8; ++ch) {
      const int k8 = cc * 16 + ch * 2 + half;
      const size_t a = (((size_t)tn * 64 + k8) * 64 + rt + l31) * 8;
      const bf16x8 ah = *reinterpret_cast<const bf16x8*>(xh + a);
      const bf16x8 al = *reinterpret_cast<const bf16x8*>(xl + a);
      acc = MF(ah, BH[ch], acc); acc = MF(ah, BL[ch], acc); acc = MF(al, BH[ch], acc);
    }
  }

  float M = acc[0];
#pragma unroll
  for (int i = 1; i < 16; ++i) M = fmaxf(M, acc[i]);
  M = fmaxf(M, __shfl_xor(M, 32));
  fr[w * 32 + l31] = M;
  __syncthreads();
  if (t < 64) {
    const float Mc = fmaxf(fr[t], fr[64 + t]);
    const unsigned ub = __float_as_uint(Mc);
    const unsigned key = (ub & 0x80000000u) ? ~ub : (ub | 0x80000000u);
    atomicMax(outenc + b * 1024 + o0 + t, key);
  }
}

__global__ __launch_bounds__(256) void decode_kernel(const unsigned int* __restrict__ enc,
    const float* __restrict__ bf, float* __restrict__ out) {
  const int gid = blockIdx.x * 256 + threadIdx.x;  // 8192
  const unsigned key = enc[gid];
  const unsigned ubits = (key & 0x80000000u) ? (key & 0x7fffffffu) : ~key;
  out[gid] = __uint_as_float(ubits) + bf[gid & 1023];
}

// ---------------- launch ----------------
extern "C" void kernel_launch(void* const* d_in, const int* in_sizes, int n_in,
                              void* d_out, int out_size, void* d_ws, size_t ws_size,
                              hipStream_t stream) {
  (void)in_sizes; (void)n_in; (void)out_size; (void)ws_size;
  const float* x   = (const float*)d_in[0];
  const float* W0  = (const float*)d_in[1];
  const float* b0  = (const float*)d_in[2];
  const float* g0  = (const float*)d_in[3];
  const float* be0 = (const float*)d_in[4];
  const float* W1  = (const float*)d_in[5];
  const float* b1  = (const float*)d_in[6];
  const float* g1  = (const float*)d_in[7];
  const float* be1 = (const float*)d_in[8];
  const float* W2  = (const float*)d_in[9];
  const float* b2  = (const float*)d_in[10];
  const float* g2  = (const float*)d_in[11];
  const float* be2 = (const float*)d_in[12];
  const float* W3  = (const float*)d_in[13];
  const float* b3  = (const float*)d_in[14];
  const float* g3  = (const float*)d_in[15];
  const float* be3 = (const float*)d_in[16];
  const float* Wf  = (const float*)d_in[17];
  const float* bf  = (const float*)d_in[18];

  float* wsf = (float*)d_ws;
  int* idxb = (int*)d_ws;                        // 327,680 ints
  float* stats = wsf + 327680;                   // 2048
  float* nb = wsf + 329728;                      // 4 x 16384 norm buffers
  unsigned* outenc = (unsigned*)(wsf + 395264);  // 8192
  float* x4 = wsf + 403456;                      // 65536
  float* featA = wsf + 468992;                   // 16384*256
  float* negd = wsf + 4663296;                   // 4*2048*2048 (67 MB)
  float* Yb = negd;                              // alias (disjoint phases)
  float* Tb = negd + 4194304;
  unsigned short* xh = (unsigned short*)(wsf + 21440512);  // xT hi plane
  unsigned short* xl = xh + 8388608;                       // xT lo plane
  unsigned short* wb1 = xl + 8388608;            // 2*(2*64*64)   = 16384
  unsigned short* wb2 = wb1 + 16384;             // 2*(2*128*64)  = 32768
  unsigned short* wb3 = wb2 + 32768;             // 2*(2*256*128) = 131072
  unsigned short* wfh = wb3 + 131072;            // 1024*512
  unsigned short* wfl = wfh + 524288;

  float* normsA = nb, *normsB = nb + 16384, *normsC = nb + 32768, *normsD = nb + 49152;

  hipMemsetAsync(stats, 0, (2048 + 65536) * sizeof(float), stream);
  hipMemsetAsync(outenc, 0, 8192 * sizeof(unsigned), stream);

  const dim3 blk(256, 1, 1);
  const dim3 ggrid(32, 32, 4);
  const dim3 sgrid(2048, 1, 1);
  const dim3 ergrid(512, 1, 1);

  pad_norms<<<dim3(64), blk, 0, stream>>>(x, x4, normsA);
  wsplit_all<<<dim3(2224), blk, 0, stream>>>(W1, W2, W3, Wf, wb1, wb2, wb3, wfh, wfl);

  // Layer 0 (C=3 -> 64, out cols [0,64))
  for (int cb = 0; cb < 2; ++cb) {
    dist0_kernel<<<ggrid, blk, 0, stream>>>(x4, normsA, negd, 4 * cb);
    knn_select_kernel<<<sgrid, blk, 0, stream>>>(negd, idxb, 4 * cb);
  }
  pt_gemm0<<<dim3(4096), blk, 0, stream>>>(x, W0, b0, Yb, Tb);
  edge_reduce<64><<<ergrid, blk, 0, stream>>>(Yb, Tb, idxb, featA, stats, stats + 256);
  bnrelu_kernel<64, true><<<dim3(512), blk, 0, stream>>>(featA, stats, stats + 256,
      g0, be0, xh, xl, 0, normsB);

  // Layer 1 (64 -> 64, in cols [0,64), out [64,128))
  for (int cb = 0; cb < 2; ++cb) {
    dist_mfma<64><<<ggrid, blk, 0, stream>>>(xh, xl, 0, normsB, negd, 4 * cb);
    knn_select_kernel<<<sgrid, blk, 0, stream>>>(negd, idxb, 4 * cb);
  }
  pt_gemm<64, 128><<<dim3(256, 2), blk, 0, stream>>>(xh, xl, 0, wb1, wb1 + 8192, b1, Yb, Tb);
  edge_reduce<64><<<ergrid, blk, 0, stream>>>(Yb, Tb, idxb, featA, stats + 512, stats + 768);
  bnrelu_kernel<64, true><<<dim3(512), blk, 0, stream>>>(featA, stats + 512, stats + 768,
      g1, be1, xh, xl, 64, normsC);

  // Layer 2 (64 -> 128, in cols [64,128), out [128,256))
  for (int cb = 0; cb < 2; ++cb) {
    dist_mfma<64><<<ggrid, blk, 0, stream>>>(xh, xl, 64, normsC, negd, 4 * cb);
    knn_select_kernel<<<sgrid, blk, 0, stream>>>(negd, idxb, 4 * cb);
  }
  pt_gemm<64, 256><<<dim3(256, 4), blk, 0, stream>>>(xh, xl, 64, wb2, wb2 + 16384, b2, Yb, Tb);
  edge_reduce<128><<<ergrid, blk, 0, stream>>>(Yb, Tb, idxb, featA, stats + 1024, stats + 1280);
  bnrelu_kernel<128, true><<<dim3(1024), blk, 0, stream>>>(featA, stats + 1024, stats + 1280,
      g2, be2, xh, xl, 128, normsD);

  // Layer 3 (128 -> 256, in cols [128,256), out [256,512))
  for (int cb = 0; cb < 2; ++cb) {
    dist_mfma<128><<<ggrid, blk, 0, stream>>>(xh, xl, 128, normsD, negd, 4 * cb);
    knn_select_kernel<<<sgrid, blk, 0, stream>>>(negd, idxb, 4 * cb);
  }
  pt_gemm<128, 512><<<dim3(256, 8), blk, 0, stream>>>(xh, xl, 128, wb3, wb3 + 65536, b3, Yb, Tb);
  edge_reduce<256><<<ergrid, blk, 0, stream>>>(Yb, Tb, idxb, featA, stats + 1536, stats + 1792);
  bnrelu_kernel<256, false><<<dim3(2048), blk, 0, stream>>>(featA, stats + 1536, stats + 1792,
      g3, be3, xh, xl, 256, nullptr);

  // Final 1x1 conv + global max pool
  final_mfma<<<dim3(32, 16, 8), blk, 0, stream>>>(xh, xl, wfh, wfl, outenc);
  decode_kernel<<<dim3(32), blk, 0, stream>>>(outenc, bf, (float*)d_out);
}